// Round 7
// baseline (95.794 us; speedup 1.0000x reference)
//
#include <hip/hip_runtime.h>
#include <math.h>

// TripletHard B=8192 D=128 NC=256. Round-26: CLASS-SORTED ROWS -> the class
// masks leave the inner loop. Evidence across r20-r25: kernel is insensitive
// to memory-path changes (staging/direct, barriers, pins: +-1us) but costs
// ~2.5-3us per epilogue-op-per-element (r20: +5 ops -> +11us). So the fused
// per-element mask-and-min chain (~6 ops/elem) is the cost center, not L2 or
// barriers. Fix: prep scatters rows sorted by label (hist+scan+atomic
// scatter). Same-class cols are then a contiguous run per row; a 128-row
// block's classes span ~130 contiguous cols -> only ~5-6 of its 256
// (block,jt) tiles can contain same-class pairs (computed from base[]).
// All other tiles run a LEAN epilogue: n1 = min3(n1, v0, v1) -- 3 ops/pair
// vs 12. Masked tiles keep the full label-compare + ss1 + self-exclusion
// (r24's verified dd formula). Permutation-invariant: same distance
// multisets, min order-invariant, mean order-invariant.
//   hist : 1 block; label histogram + exclusive scan -> base[257], cursor.
//   prep : fp32->bf16 (RNE), scatter to sorted slot dst=atomicAdd(cursor),
//          K-major fbT, lsq[dst]=(sq,lblbits). 8 thr/row.
//   work : 1024 blocks (64 i-blocks x 16 stripes), 4 waves, tile 32x32/wave,
//          lb(256,4) -> 4 blocks/CU. B via LDS dbuf (global_load_lds),
//          16 jt, lean/masked epilogue per jt (wave-uniform branch).
//   merge: min over 16 (n1,ss1) slices -> mean hinge (device atomics).
// fbT8[kc*8192 + srow] = features[orig(srow)][kc*8..kc*8+7], kc=0..15.

#define BN 8192
#define MARGIN_F 1.0f
#define EPS_F 1e-5f

typedef __attribute__((ext_vector_type(8))) short short8;
typedef __attribute__((ext_vector_type(4))) float floatx4;

__device__ __forceinline__ unsigned short bf16_rne(float x, float& r) {
    unsigned u = __float_as_uint(x);
    u += 0x7FFF + ((u >> 16) & 1);
    unsigned short h = (unsigned short)(u >> 16);
    r = __uint_as_float(((unsigned)h) << 16);
    return h;
}

// 1 block: label histogram -> exclusive scan -> base[0..256], cursor init.
// Also zero-inits g_acc/counter.
__global__ __launch_bounds__(256) void hist_kernel(const int* __restrict__ lbl,
                                                   int* __restrict__ base,
                                                   int* __restrict__ cursor,
                                                   float* __restrict__ g_acc,
                                                   unsigned* __restrict__ counter) {
    __shared__ int h[256];
    __shared__ int sc[257];
    const int t = threadIdx.x;
    if (t == 0) { *g_acc = 0.f; *counter = 0u; }
    h[t] = 0;
    __syncthreads();
    const int4* l4 = (const int4*)lbl;
    for (int i = t; i < BN / 4; i += 256) {
        int4 L = l4[i];
        atomicAdd(&h[L.x], 1);
        atomicAdd(&h[L.y], 1);
        atomicAdd(&h[L.z], 1);
        atomicAdd(&h[L.w], 1);
    }
    __syncthreads();
    if (t == 0) sc[0] = 0;
    sc[t + 1] = h[t];
    __syncthreads();
    for (int off = 1; off < 256; off <<= 1) {
        int add = (t >= off) ? sc[t + 1 - off] : 0;
        __syncthreads();
        sc[t + 1] += add;
        __syncthreads();
    }
    base[t] = sc[t];
    cursor[t] = sc[t];
    if (t == 255) base[256] = sc[256];
}

// 8 threads/row (256 blocks): bf16 convert, K-major scatter to sorted slot,
// lsq=(sq, lblbits) of rounded values.
__global__ __launch_bounds__(256) void prep_kernel(const float* __restrict__ f,
                                                   const int* __restrict__ lbl,
                                                   int* __restrict__ cursor,
                                                   short8* __restrict__ fbT,
                                                   float2* __restrict__ lsq) {
    int gid = blockIdx.x * 256 + threadIdx.x;  // 0..65535
    int row = gid >> 3, part = gid & 7;
    int lb = lbl[row];
    int dst = 0;
    if (part == 0) dst = atomicAdd(&cursor[lb], 1);
    dst = __shfl(dst, 0, 8);  // broadcast within the 8-thread row group

    const float4* f4 = (const float4*)f + (size_t)row * 32 + part * 4;
    float s = 0.f;
#pragma unroll
    for (int cc = 0; cc < 2; ++cc) {  // chunk kc = part*2 + cc
        float4 v0 = f4[cc * 2], v1 = f4[cc * 2 + 1];
        float r0, r1, r2, r3, r4, r5, r6, r7;
        short8 o;
        o[0] = (short)bf16_rne(v0.x, r0);
        o[1] = (short)bf16_rne(v0.y, r1);
        o[2] = (short)bf16_rne(v0.z, r2);
        o[3] = (short)bf16_rne(v0.w, r3);
        o[4] = (short)bf16_rne(v1.x, r4);
        o[5] = (short)bf16_rne(v1.y, r5);
        o[6] = (short)bf16_rne(v1.z, r6);
        o[7] = (short)bf16_rne(v1.w, r7);
        fbT[(size_t)(part * 2 + cc) * BN + dst] = o;
        s += r0 * r0 + r1 * r1 + r2 * r2 + r3 * r3 +
             r4 * r4 + r5 * r5 + r6 * r6 + r7 * r7;
    }
    s += __shfl_xor(s, 1, 8);
    s += __shfl_xor(s, 2, 8);
    s += __shfl_xor(s, 4, 8);
    if (part == 0) {
        float2 p;
        p.x = s;
        p.y = __int_as_float(lb);
        lsq[dst] = p;
    }
}

// Stage one 32-col B-tile (16 chunks x 32 cols = 8 KB) into LDS: each wave
// issues 2 global_load_lds(16B). LDS dest is wave-uniform; HW adds lane*16.
// Layout: tile[kc*32 + col], kc = lane>>5 within each 64-slot instr.
__device__ __forceinline__ void stage_tile(const short8* __restrict__ fbT,
                                           short8* tile, int j0, int wv, int lane) {
#pragma unroll
    for (int it = 0; it < 2; ++it) {
        int s = wv * 128 + it * 64;  // wave-uniform slot base
        int kc = (s >> 5) + (lane >> 5);
        int col = lane & 31;
        const short8* g = fbT + ((size_t)kc * BN + j0 + col);
        __builtin_amdgcn_global_load_lds(
            (const __attribute__((address_space(1))) void*)g,
            (__attribute__((address_space(3))) void*)(tile + s),
            16, 0, 0);
    }
}

// Fused work kernel: 1024 blocks (4/CU), 4 waves, wave tile 32x32.
// Lean tiles (no same-class pairs possible): n1 = min3(n1, v0, v1).
// Masked tiles ([jtLo,jtHi] from class-run intersection): full label mask,
// ss1 tracking, self-exclusion via dd == nf*16 - mf*16 - rg (r24-verified).
__global__ __launch_bounds__(256, 4) void work_kernel(const short8* __restrict__ fbT,
                                                      const float2* __restrict__ lsq,
                                                      const int* __restrict__ base,
                                                      float* __restrict__ part_n1,
                                                      float* __restrict__ part_p1) {
    const int t = threadIdx.x;
    const int lane = t & 63;
    const int wv = t >> 6;
    const int q = lane >> 4, c = lane & 15;
    const int bid = blockIdx.x;

    __shared__ short8 Bt[2][512];   // 2 x 8 KB double buffer, [kc*32 + col]
    __shared__ float2 lsq_sh[512];  // block's j-stripe (sq, lblbits) — 4 KB

    const int ib = bid & 63;         // 64 i-blocks of 128 rows
    const int g = bid >> 6;          // 16 stripes
    const int i0 = ib * 128 + wv * 32;
    const int jb = g * 512;

    stage_tile(fbT, Bt[0], jb, wv, lane);  // tile 0 in flight

    // stage the stripe's (sq,label) once: 512 float2, 2 per thread
    lsq_sh[t] = lsq[jb + t];
    lsq_sh[t + 256] = lsq[jb + t + 256];

    // masked-jt range: block rows are sorted, classes cLo..cHi; their class
    // columns live in [base[cLo], base[cHi+1]) -- intersect with the stripe.
    const int ibase = ib * 128;
    const int cLo = __float_as_int(lsq[ibase].y);
    const int cHi = __float_as_int(lsq[ibase + 127].y);
    const int jLoCol = base[cLo];
    const int jHiCol = base[cHi + 1];  // exclusive
    const int mLo = jLoCol > jb ? jLoCol : jb;
    const int mHi = jHiCol < jb + 512 ? jHiCol : jb + 512;
    const bool blkmask = mLo < mHi;
    const int jtLo = blkmask ? (mLo - jb) >> 5 : 16;
    const int jtHi = blkmask ? (mHi - 1 - jb) >> 5 : -1;

    short8 a[2][4];
#pragma unroll
    for (int mf = 0; mf < 2; ++mf) {
        int row = i0 + mf * 16 + c;
#pragma unroll
        for (int ks = 0; ks < 4; ++ks)
            a[mf][ks] = fbT[(size_t)(ks * 4 + q) * BN + row];
    }
    int li[2][4];
#pragma unroll
    for (int mf = 0; mf < 2; ++mf)
#pragma unroll
        for (int rg = 0; rg < 4; ++rg)
            li[mf][rg] = __float_as_int(lsq[i0 + mf * 16 + q * 4 + rg].y);

    float n1[2][4], ss1[2][4];
#pragma unroll
    for (int mf = 0; mf < 2; ++mf)
#pragma unroll
        for (int rg = 0; rg < 4; ++rg) {
            n1[mf][rg] = INFINITY;
            ss1[mf][rg] = INFINITY;
        }

    __syncthreads();  // tile 0 + lsq_sh resident

    for (int jt = 0; jt < 16; ++jt) {
        const short8* cur = Bt[jt & 1];
        // prefetch next tile NOW; it lands during this tile's compute
        if (jt < 15) stage_tile(fbT, Bt[1 - (jt & 1)], jb + (jt + 1) * 32, wv, lane);

        float sjv[2]; int ljv[2];
#pragma unroll
        for (int nf = 0; nf < 2; ++nf) {
            float2 p = lsq_sh[jt * 32 + nf * 16 + c];
            sjv[nf] = p.x;
            ljv[nf] = __float_as_int(p.y);
        }

        // b-frags from LDS
        short8 b[4][2];
#pragma unroll
        for (int ks = 0; ks < 4; ++ks)
#pragma unroll
            for (int nf = 0; nf < 2; ++nf)
                b[ks][nf] = cur[(ks * 4 + q) * 32 + nf * 16 + c];

        floatx4 acc[2][2];
#pragma unroll
        for (int mf = 0; mf < 2; ++mf)
#pragma unroll
            for (int nf = 0; nf < 2; ++nf) acc[mf][nf] = (floatx4)0.f;

#pragma unroll
        for (int ks = 0; ks < 4; ++ks)
#pragma unroll
            for (int mf = 0; mf < 2; ++mf)
#pragma unroll
                for (int nf = 0; nf < 2; ++nf)
                    acc[mf][nf] = __builtin_amdgcn_mfma_f32_16x16x32_bf16(
                        a[mf][ks], b[ks][nf], acc[mf][nf], 0, 0, 0);

        if (jt >= jtLo && jt <= jtHi) {
            // ---- masked tile: full label compare + ss1 + self-exclusion
            int dd = (i0 + q * 4) - (jb + jt * 32 + c);  // i-j = dd+mf*16+rg-nf*16
#pragma unroll
            for (int mf = 0; mf < 2; ++mf)
#pragma unroll
                for (int rg = 0; rg < 4; ++rg) {
                    float v0 = fmaf(-2.0f, acc[mf][0][rg], sjv[0]);
                    float v1 = fmaf(-2.0f, acc[mf][1][rg], sjv[1]);
                    bool sm0 = (li[mf][rg] == ljv[0]);
                    bool sm1 = (li[mf][rg] == ljv[1]);
                    float vd0 = sm0 ? INFINITY : v0;
                    float vd1 = sm1 ? INFINITY : v1;
                    n1[mf][rg] = fminf(fminf(n1[mf][rg], vd0), vd1);
                    bool ex0 = sm0 && (dd != (0 * 16 - mf * 16 - rg));
                    bool ex1 = sm1 && (dd != (1 * 16 - mf * 16 - rg));
                    float vs0 = ex0 ? v0 : INFINITY;
                    float vs1 = ex1 ? v1 : INFINITY;
                    ss1[mf][rg] = fminf(fminf(ss1[mf][rg], vs0), vs1);
                }
        } else {
            // ---- lean tile: provably no same-class pair -> pure min
#pragma unroll
            for (int mf = 0; mf < 2; ++mf)
#pragma unroll
                for (int rg = 0; rg < 4; ++rg) {
                    float v0 = fmaf(-2.0f, acc[mf][0][rg], sjv[0]);
                    float v1 = fmaf(-2.0f, acc[mf][1][rg], sjv[1]);
                    n1[mf][rg] = fminf(fminf(n1[mf][rg], v0), v1);
                }
        }
        // barrier at END: reads of cur done before next stage overwrites;
        // the stage issued above had the whole compute phase to land.
        __syncthreads();
    }

    // min-reduce across the 16 c-lanes sharing each accumulator row
#pragma unroll
    for (int m = 1; m < 16; m <<= 1) {
#pragma unroll
        for (int mf = 0; mf < 2; ++mf)
#pragma unroll
            for (int rg = 0; rg < 4; ++rg) {
                n1[mf][rg] = fminf(n1[mf][rg], __shfl_xor(n1[mf][rg], m, 16));
                ss1[mf][rg] = fminf(ss1[mf][rg], __shfl_xor(ss1[mf][rg], m, 16));
            }
    }
    if (c == 0) {
#pragma unroll
        for (int mf = 0; mf < 2; ++mf)
#pragma unroll
            for (int rg = 0; rg < 4; ++rg) {
                int idx = g * BN + i0 + mf * 16 + q * 4 + rg;
                part_n1[idx] = n1[mf][rg];
                part_p1[idx] = ss1[mf][rg];
            }
    }
}

// combine 16 (n1,ss1) slices -> hinge; atomic sum; last block writes mean
__global__ __launch_bounds__(128) void merge_kernel(const float* __restrict__ part_n1,
                                                    const float* __restrict__ part_p1,
                                                    const float2* __restrict__ lsq,
                                                    float* __restrict__ g_acc,
                                                    unsigned* __restrict__ counter,
                                                    float* __restrict__ out) {
    int r = blockIdx.x * 128 + threadIdx.x;
    float n = INFINITY, ss = INFINITY;
#pragma unroll
    for (int k = 0; k < 16; ++k) {
        n = fminf(n, part_n1[k * BN + r]);
        ss = fminf(ss, part_p1[k * BN + r]);
    }
    float si = lsq[r].x;
    float pos = sqrtf(fmaxf(si + ss + EPS_F, 0.f));
    float neg = sqrtf(fmaxf(si + n + EPS_F, 0.f));
    float h = fmaxf(MARGIN_F + pos - neg, 0.f);
    __shared__ float red[2];
#pragma unroll
    for (int m = 32; m >= 1; m >>= 1) h += __shfl_down(h, m, 64);
    if ((threadIdx.x & 63) == 0) red[threadIdx.x >> 6] = h;
    __syncthreads();
    if (threadIdx.x == 0) {
        atomicAdd(g_acc, red[0] + red[1]);
        __threadfence();
        unsigned old = atomicAdd(counter, 1u);
        if (old == 63u) {
            float tot = atomicAdd(g_acc, 0.0f);
            out[0] = tot / (float)BN;
        }
    }
}

extern "C" void kernel_launch(void* const* d_in, const int* in_sizes, int n_in,
                              void* d_out, int out_size, void* d_ws, size_t ws_size,
                              hipStream_t stream) {
    const float* f = (const float*)d_in[0];
    const int* lbl = (const int*)d_in[1];
    char* ws = (char*)d_ws;
    float2* lsq = (float2*)ws;                                  // 64 KB
    short8* fbT = (short8*)(ws + 65536);                        // 2 MB
    float* part_n1 = (float*)(ws + 65536 + 2097152);            // 512 KB
    float* part_p1 = (float*)(ws + 65536 + 2097152 + 524288);   // 512 KB
    char* tail = ws + 65536 + 2097152 + 1048576;
    float* g_acc = (float*)tail;
    unsigned* counter = (unsigned*)(tail + 4);
    int* base = (int*)(tail + 64);      // 257 ints
    int* cursor = (int*)(tail + 2112);  // 256 ints
    float* out = (float*)d_out;

    hist_kernel<<<1, 256, 0, stream>>>(lbl, base, cursor, g_acc, counter);
    prep_kernel<<<256, 256, 0, stream>>>(f, lbl, cursor, fbT, lsq);
    work_kernel<<<1024, 256, 0, stream>>>(fbT, lsq, base, part_n1, part_p1);
    merge_kernel<<<64, 128, 0, stream>>>(part_n1, part_p1, lsq, g_acc, counter, out);
}

// Round 8
// 85.936 us; speedup vs baseline: 1.1147x; 1.1147x over previous
//
#include <hip/hip_runtime.h>
#include <math.h>

// TripletHard B=8192 D=128 NC=256. Round-27: COUNTED VMCNT PIPELINE (T4).
// r26 (class-sort) regressed +10.6us -> "epilogue ops dominate" is dead
// (lean epilogue on 98% of tiles bought nothing; hist+scattered-prep+dual
// path cost more). Reverted to r25 structure exactly. Remaining model:
// work ~37us vs ~19us zero-overlap floor; the per-jt __syncthreads compiles
// to s_waitcnt vmcnt(0)+s_barrier (compiler must drain global_load_lds),
// exposing stage latency 15x. Fix = guide T4 in minimal form: 3 LDS
// buffers, stage distance 2, barrier = {s_waitcnt vmcnt(2); s_barrier;
// sched_barrier(0)}. The just-issued stage (2 loads/wave) stays in flight
// across the barrier; the tile consumed next has had >=1 full compute
// phase + a prior counted wait -> drain ~0. Tail jt=14 uses vmcnt(0).
// Safety: buffer reuse distance 3 with one rendezvous barrier per jt ->
// no overwrite hazard; per-wave vmcnt covers own stores, barrier publishes.
//   prep : fp32->bf16 (RNE), K-major fbT, lsq=(sq,lblbits). (no sort)
//   work : 1024 blocks (64 i-blocks x 16 stripes), 4 waves, tile 32x32/wave,
//          lb(256,4) -> 4 blocks/CU. B via 3-buf LDS pipeline, 16 jt.
//          Epilogue r25-verbatim: n1 + ss1 (self-excl via dd in 64 diag
//          blocks, self <=> dd == nf*16 - mf*16 - rg).
//   merge: min over 16 (n1,ss1) slices -> mean hinge (device atomics).
// fbT8[kc*8192 + row] = features[row][kc*8..kc*8+7], kc=0..15.

#define BN 8192
#define MARGIN_F 1.0f
#define EPS_F 1e-5f

typedef __attribute__((ext_vector_type(8))) short short8;
typedef __attribute__((ext_vector_type(4))) float floatx4;

__device__ __forceinline__ unsigned short bf16_rne(float x, float& r) {
    unsigned u = __float_as_uint(x);
    u += 0x7FFF + ((u >> 16) & 1);
    unsigned short h = (unsigned short)(u >> 16);
    r = __uint_as_float(((unsigned)h) << 16);
    return h;
}

// 8 threads/row (256 blocks): bf16 convert, K-major write, lsq=(sq, lblbits)
// from ROUNDED values. Also zero-inits g_acc/counter.
__global__ __launch_bounds__(256) void prep_kernel(const float* __restrict__ f,
                                                   const int* __restrict__ lbl,
                                                   short8* __restrict__ fbT,
                                                   float2* __restrict__ lsq,
                                                   float* __restrict__ g_acc,
                                                   unsigned* __restrict__ counter) {
    int gid = blockIdx.x * 256 + threadIdx.x;  // 0..65535
    if (gid == 0) { *g_acc = 0.f; *counter = 0u; }
    int row = gid >> 3, part = gid & 7;
    const float4* f4 = (const float4*)f + (size_t)row * 32 + part * 4;
    float s = 0.f;
#pragma unroll
    for (int cc = 0; cc < 2; ++cc) {  // chunk kc = part*2 + cc
        float4 v0 = f4[cc * 2], v1 = f4[cc * 2 + 1];
        float r0, r1, r2, r3, r4, r5, r6, r7;
        short8 o;
        o[0] = (short)bf16_rne(v0.x, r0);
        o[1] = (short)bf16_rne(v0.y, r1);
        o[2] = (short)bf16_rne(v0.z, r2);
        o[3] = (short)bf16_rne(v0.w, r3);
        o[4] = (short)bf16_rne(v1.x, r4);
        o[5] = (short)bf16_rne(v1.y, r5);
        o[6] = (short)bf16_rne(v1.z, r6);
        o[7] = (short)bf16_rne(v1.w, r7);
        fbT[(size_t)(part * 2 + cc) * BN + row] = o;
        s += r0 * r0 + r1 * r1 + r2 * r2 + r3 * r3 +
             r4 * r4 + r5 * r5 + r6 * r6 + r7 * r7;
    }
    s += __shfl_xor(s, 1, 8);
    s += __shfl_xor(s, 2, 8);
    s += __shfl_xor(s, 4, 8);
    if (part == 0) {
        float2 p;
        p.x = s;
        p.y = __int_as_float(lbl[row]);
        lsq[row] = p;
    }
}

// Stage one 32-col B-tile (16 chunks x 32 cols = 8 KB) into LDS: each wave
// issues 2 global_load_lds(16B). LDS dest is wave-uniform; HW adds lane*16.
// Layout: tile[kc*32 + col], kc = lane>>5 within each 64-slot instr.
__device__ __forceinline__ void stage_tile(const short8* __restrict__ fbT,
                                           short8* tile, int j0, int wv, int lane) {
#pragma unroll
    for (int it = 0; it < 2; ++it) {
        int s = wv * 128 + it * 64;  // wave-uniform slot base
        int kc = (s >> 5) + (lane >> 5);
        int col = lane & 31;
        const short8* g = fbT + ((size_t)kc * BN + j0 + col);
        __builtin_amdgcn_global_load_lds(
            (const __attribute__((address_space(1))) void*)g,
            (__attribute__((address_space(3))) void*)(tile + s),
            16, 0, 0);
    }
}

// The 16-jt inner loop: 3-buffer LDS pipeline, stage distance 2, counted
// vmcnt barriers. DIAG adds index-based self exclusion for ss1:
// self <=> dd == nf*16 - mf*16 - rg (r24-verified).
template <bool DIAG>
__device__ __forceinline__ void jt_loop(const short8* __restrict__ fbT,
                                        short8 (*Bt)[512],
                                        const float2* lsq_sh,
                                        const short8 a[2][4], const int li[2][4],
                                        float n1[2][4], float ss1[2][4],
                                        int wv, int lane, int c, int q,
                                        int i0, int jb) {
    for (int jt = 0; jt < 16; ++jt) {
        // stage tile jt+2 (distance 2): it gets two compute phases + one
        // counted wait before anyone reads it
        if (jt < 14) stage_tile(fbT, Bt[(jt + 2) % 3], jb + (jt + 2) * 32, wv, lane);
        const short8* cur = Bt[jt % 3];

        int ljv[2]; float sjv[2];
#pragma unroll
        for (int nf = 0; nf < 2; ++nf) {
            float2 p = lsq_sh[jt * 32 + nf * 16 + c];
            sjv[nf] = p.x;
            ljv[nf] = __float_as_int(p.y);
        }

        // i - j = dd + mf*16 + rg - nf*16
        int dd = DIAG ? ((i0 + q * 4) - (jb + jt * 32 + c)) : 0;

        // b-frags from LDS (contiguous 1KB rows per instr, conflict-free)
        short8 b[4][2];
#pragma unroll
        for (int ks = 0; ks < 4; ++ks)
#pragma unroll
            for (int nf = 0; nf < 2; ++nf)
                b[ks][nf] = cur[(ks * 4 + q) * 32 + nf * 16 + c];

        floatx4 acc[2][2];
#pragma unroll
        for (int mf = 0; mf < 2; ++mf)
#pragma unroll
            for (int nf = 0; nf < 2; ++nf) acc[mf][nf] = (floatx4)0.f;

#pragma unroll
        for (int ks = 0; ks < 4; ++ks)
#pragma unroll
            for (int mf = 0; mf < 2; ++mf)
#pragma unroll
                for (int nf = 0; nf < 2; ++nf)
                    acc[mf][nf] = __builtin_amdgcn_mfma_f32_16x16x32_bf16(
                        a[mf][ks], b[ks][nf], acc[mf][nf], 0, 0, 0);

#pragma unroll
        for (int nf = 0; nf < 2; ++nf)
#pragma unroll
            for (int mf = 0; mf < 2; ++mf)
#pragma unroll
                for (int rg = 0; rg < 4; ++rg) {
                    float v = fmaf(-2.0f, acc[mf][nf][rg], sjv[nf]);
                    bool same = (li[mf][rg] == ljv[nf]);
                    float vd = same ? INFINITY : v;
                    n1[mf][rg] = fminf(n1[mf][rg], vd);
                    bool excl = same;
                    if (DIAG) excl = same && (dd != (nf * 16 - mf * 16 - rg));
                    float vs = excl ? v : INFINITY;
                    ss1[mf][rg] = fminf(ss1[mf][rg], vs);
                }

        // counted-vmcnt barrier (T4): let the just-issued stage (2 loads/
        // wave) stay in flight; only older stages must have retired. The
        // tile read next iter was staged 2 iters ago -> ready. jt=14 has no
        // new stage in flight and tile15 must land -> vmcnt(0) once.
        if (jt < 15) {
            if (jt == 14)
                asm volatile("s_waitcnt vmcnt(0)" ::: "memory");
            else
                asm volatile("s_waitcnt vmcnt(2)" ::: "memory");
            __builtin_amdgcn_s_barrier();
            __builtin_amdgcn_sched_barrier(0);  // keep next ds_reads below
        }
    }
}

// Fused work kernel: 1024 blocks (4/CU), 4 waves, wave tile 32x32.
// Per element: n1 = min diff-class v, ss1 = min same-class v excl self.
__global__ __launch_bounds__(256, 4) void work_kernel(const short8* __restrict__ fbT,
                                                      const float2* __restrict__ lsq,
                                                      float* __restrict__ part_n1,
                                                      float* __restrict__ part_p1) {
    const int t = threadIdx.x;
    const int lane = t & 63;
    const int wv = t >> 6;
    const int q = lane >> 4, c = lane & 15;
    const int bid = blockIdx.x;

    __shared__ short8 Bt[3][512];   // 3 x 8 KB pipeline buffers, [kc*32+col]
    __shared__ float2 lsq_sh[512];  // block's j-stripe (sq, lblbits) — 4 KB

    const int ib = bid & 63;         // 64 i-blocks of 128 rows
    const int g = bid >> 6;          // 16 stripes
    const int i0 = ib * 128 + wv * 32;
    const int jb = g * 512;
    const bool diag = ((ib >> 2) == g);  // i-range intersects j-stripe

    stage_tile(fbT, Bt[0], jb, wv, lane);       // tile 0 in flight
    stage_tile(fbT, Bt[1], jb + 32, wv, lane);  // tile 1 in flight

    // stage the stripe's (sq,label) once: 512 float2, 2 per thread
    lsq_sh[t] = lsq[jb + t];
    lsq_sh[t + 256] = lsq[jb + t + 256];

    short8 a[2][4];
#pragma unroll
    for (int mf = 0; mf < 2; ++mf) {
        int row = i0 + mf * 16 + c;
#pragma unroll
        for (int ks = 0; ks < 4; ++ks)
            a[mf][ks] = fbT[(size_t)(ks * 4 + q) * BN + row];
    }
    int li[2][4];
#pragma unroll
    for (int mf = 0; mf < 2; ++mf)
#pragma unroll
        for (int rg = 0; rg < 4; ++rg)
            li[mf][rg] = __float_as_int(lsq[i0 + mf * 16 + q * 4 + rg].y);

    float n1[2][4], ss1[2][4];
#pragma unroll
    for (int mf = 0; mf < 2; ++mf)
#pragma unroll
        for (int rg = 0; rg < 4; ++rg) {
            n1[mf][rg] = INFINITY;
            ss1[mf][rg] = INFINITY;
        }

    __syncthreads();  // one-time full drain: tiles 0,1 + lsq_sh resident

    if (diag)
        jt_loop<true>(fbT, Bt, lsq_sh, a, li, n1, ss1, wv, lane, c, q, i0, jb);
    else
        jt_loop<false>(fbT, Bt, lsq_sh, a, li, n1, ss1, wv, lane, c, q, i0, jb);

    // min-reduce across the 16 c-lanes sharing each accumulator row
#pragma unroll
    for (int m = 1; m < 16; m <<= 1) {
#pragma unroll
        for (int mf = 0; mf < 2; ++mf)
#pragma unroll
            for (int rg = 0; rg < 4; ++rg) {
                n1[mf][rg] = fminf(n1[mf][rg], __shfl_xor(n1[mf][rg], m, 16));
                ss1[mf][rg] = fminf(ss1[mf][rg], __shfl_xor(ss1[mf][rg], m, 16));
            }
    }
    if (c == 0) {
#pragma unroll
        for (int mf = 0; mf < 2; ++mf)
#pragma unroll
            for (int rg = 0; rg < 4; ++rg) {
                int idx = g * BN + i0 + mf * 16 + q * 4 + rg;
                part_n1[idx] = n1[mf][rg];
                part_p1[idx] = ss1[mf][rg];
            }
    }
}

// combine 16 (n1,ss1) slices -> hinge; atomic sum; last block writes mean
__global__ __launch_bounds__(128) void merge_kernel(const float* __restrict__ part_n1,
                                                    const float* __restrict__ part_p1,
                                                    const float2* __restrict__ lsq,
                                                    float* __restrict__ g_acc,
                                                    unsigned* __restrict__ counter,
                                                    float* __restrict__ out) {
    int r = blockIdx.x * 128 + threadIdx.x;
    float n = INFINITY, ss = INFINITY;
#pragma unroll
    for (int k = 0; k < 16; ++k) {
        n = fminf(n, part_n1[k * BN + r]);
        ss = fminf(ss, part_p1[k * BN + r]);
    }
    float si = lsq[r].x;
    float pos = sqrtf(fmaxf(si + ss + EPS_F, 0.f));
    float neg = sqrtf(fmaxf(si + n + EPS_F, 0.f));
    float h = fmaxf(MARGIN_F + pos - neg, 0.f);
    __shared__ float red[2];
#pragma unroll
    for (int m = 32; m >= 1; m >>= 1) h += __shfl_down(h, m, 64);
    if ((threadIdx.x & 63) == 0) red[threadIdx.x >> 6] = h;
    __syncthreads();
    if (threadIdx.x == 0) {
        atomicAdd(g_acc, red[0] + red[1]);
        __threadfence();
        unsigned old = atomicAdd(counter, 1u);
        if (old == 63u) {
            float tot = atomicAdd(g_acc, 0.0f);
            out[0] = tot / (float)BN;
        }
    }
}

extern "C" void kernel_launch(void* const* d_in, const int* in_sizes, int n_in,
                              void* d_out, int out_size, void* d_ws, size_t ws_size,
                              hipStream_t stream) {
    const float* f = (const float*)d_in[0];
    const int* lbl = (const int*)d_in[1];
    char* ws = (char*)d_ws;
    float2* lsq = (float2*)ws;                                  // 64 KB
    short8* fbT = (short8*)(ws + 65536);                        // 2 MB
    float* part_n1 = (float*)(ws + 65536 + 2097152);            // 512 KB
    float* part_p1 = (float*)(ws + 65536 + 2097152 + 524288);   // 512 KB
    float* g_acc = (float*)(ws + 65536 + 2097152 + 1048576);
    unsigned* counter = (unsigned*)(g_acc + 1);
    float* out = (float*)d_out;

    prep_kernel<<<256, 256, 0, stream>>>(f, lbl, fbT, lsq, g_acc, counter);
    work_kernel<<<1024, 256, 0, stream>>>(fbT, lsq, part_n1, part_p1);
    merge_kernel<<<64, 128, 0, stream>>>(part_n1, part_p1, lsq, g_acc, counter, out);
}